// Round 2
// baseline (324.897 us; speedup 1.0000x reference)
//
#include <hip/hip_runtime.h>
#include <hip/hip_bf16.h>

// ExplaiNN inference, float32 in/out, fp32 compute.
// B=256, L=1000, G=300, K=19, HID=100, CLS=2, P=100
//
// Stage 1: fused conv(4->G,k=19,pad=9)+BN1+ReLU+maxpool(10) -> pooled[B,G,P] f32 (ws)
// Stage 2: per-group MLP -> h2ws[G,B] f32 (ws)
// Stage 3: classifier -> out[B,2] f32

constexpr int Bn = 256, Ln = 1000, Gn = 300, HIDn = 100, Pn = 100;
constexpr int GB1 = 25;                 // groups per block, stage 1 (300/25 = 12 blocks in y)
constexpr float EPSf = 1e-5f;

// ---------------- Stage 1: conv + bn1 + relu + maxpool10 ----------------
// grid (256, 12), block 256. thread = (group gl<25, slot<10); slot owns p = slot*10..slot*10+9.
// Weights for the thread's group live in 76 VGPRs (amortized over 10 pool cells).
__global__ __launch_bounds__(256) void conv_pool_kernel(
    const float* __restrict__ x, const float* __restrict__ conv_w, const float* __restrict__ conv_b,
    const float* __restrict__ g1, const float* __restrict__ be1,
    const float* __restrict__ m1, const float* __restrict__ v1,
    float* __restrict__ pooled)
{
    __shared__ __align__(8) float xs[4 * 1018];   // x[b] zero-padded by 9 each side
    __shared__ float wsm[GB1 * 76];
    __shared__ float sA[GB1], sB[GB1];

    const int tid = threadIdx.x;
    const int b = blockIdx.x;
    const int g0 = blockIdx.y * GB1;

    for (int i = tid; i < 4 * 1018; i += 256) {
        int c = i / 1018, j = i - c * 1018, l = j - 9;
        xs[i] = ((unsigned)l < (unsigned)Ln) ? x[b * 4000 + c * 1000 + l] : 0.f;
    }
    for (int i = tid; i < GB1 * 76; i += 256)
        wsm[i] = conv_w[(size_t)g0 * 76 + i];
    if (tid < GB1) {
        int g = g0 + tid;
        float A = g1[g] * rsqrtf(v1[g] + EPSf);
        sA[tid] = A;
        sB[tid] = (conv_b[g] - m1[g]) * A + be1[g];
    }
    __syncthreads();

    if (tid < GB1 * 10) {
        const int gl = tid / 10, slot = tid - gl * 10;
        float w[76];
#pragma unroll
        for (int r = 0; r < 76; ++r) w[r] = wsm[gl * 76 + r];
        const float A = sA[gl], Bv = sB[gl];
        float* outp = pooled + ((size_t)b * Gn + (g0 + gl)) * Pn;

        for (int pp = 0; pp < 10; ++pp) {
            const int p = slot * 10 + pp;
            const int l0 = p * 10;                 // always even -> 8B-aligned float2 reads
            float acc[10];
#pragma unroll
            for (int ll = 0; ll < 10; ++ll) acc[ll] = 0.f;
#pragma unroll
            for (int c = 0; c < 4; ++c) {
                float xv[28];
                const float2* xp = (const float2*)(xs + c * 1018 + l0);
#pragma unroll
                for (int j = 0; j < 14; ++j) { float2 t = xp[j]; xv[2*j] = t.x; xv[2*j+1] = t.y; }
                const float* wp = w + c * 19;
#pragma unroll
                for (int k = 0; k < 19; ++k) {
                    float wv = wp[k];
#pragma unroll
                    for (int ll = 0; ll < 10; ++ll) acc[ll] = fmaf(xv[ll + k], wv, acc[ll]);
                }
            }
            float mx = 0.f;                        // ReLU floor
#pragma unroll
            for (int ll = 0; ll < 10; ++ll) mx = fmaxf(mx, fmaf(acc[ll], A, Bv));
            outp[p] = mx;
        }
    }
}

// ---------------- Stage 2: grouped MLP ----------------
// grid (300, 8), block 256: group g, 32 batch rows. Thread tile 4h x 4b.
// W1s/poolS: row-major stride 128 with XOR chunk swizzle (key = row>>2) ->
// conflict-free b128 on both the i-sweeping staging writes and the fragment reads.
__global__ __launch_bounds__(256) void grouped_mlp_kernel(
    const float* __restrict__ pooled, const float* __restrict__ W1, const float* __restrict__ b1,
    const float* __restrict__ g2, const float* __restrict__ be2,
    const float* __restrict__ m2, const float* __restrict__ v2,
    const float* __restrict__ W2, const float* __restrict__ b2p,
    const float* __restrict__ g3, const float* __restrict__ be3,
    const float* __restrict__ m3, const float* __restrict__ v3,
    float* __restrict__ h2ws)
{
    __shared__ __align__(16) float W1s[100 * 128];   // [h][i-swizzled], 51.2 KB
    __shared__ __align__(16) float poolS[32 * 128];  // [bl][i-swizzled], 16.4 KB
    __shared__ float A2[HIDn], C2[HIDn], w2f[HIDn];
    __shared__ float red[25 * 33];

    const int tid = threadIdx.x;
    const int g = blockIdx.x;
    const int b0 = blockIdx.y * 32;
    const float* W1g = W1 + (size_t)g * (HIDn * Pn);

    // coalesced global reads (lanes sweep i); swizzled LDS writes are conflict-free
    for (int idx = tid; idx < HIDn * Pn; idx += 256) {
        int h = idx / Pn, i = idx - h * Pn;
        W1s[h * 128 + ((((i >> 2) ^ ((h >> 2) & 7)) << 2) | (i & 3))] = W1g[idx];
    }
    for (int idx = tid; idx < 32 * Pn; idx += 256) {
        int bl = idx / Pn, i = idx - bl * Pn;
        poolS[bl * 128 + ((((i >> 2) ^ ((bl >> 2) & 7)) << 2) | (i & 3))] =
            pooled[((size_t)(b0 + bl) * Gn + g) * Pn + i];
    }
    for (int h = tid; h < HIDn; h += 256) {
        float A = g2[g * HIDn + h] * rsqrtf(v2[g * HIDn + h] + EPSf);
        A2[h] = A;
        C2[h] = (b1[g * HIDn + h] - m2[g * HIDn + h]) * A + be2[g * HIDn + h];
        w2f[h] = W2[g * HIDn + h];
    }
    __syncthreads();

    const int bx = tid & 7;        // batch group 0..7  (bb0 = bx*4)
    const int hx = tid >> 3;       // hidden group, active < 25 (h0 = hx*4)
    if (hx < 25) {
        const int h0 = hx * 4, bb0 = bx * 4;
        const int wkey = hx & 7, pkey = bx & 7;
        float acc[4][4];
#pragma unroll
        for (int a = 0; a < 4; ++a)
#pragma unroll
            for (int c = 0; c < 4; ++c) acc[a][c] = 0.f;

        for (int i4 = 0; i4 < 25; ++i4) {
            float4 wr[4], pr[4];
#pragma unroll
            for (int hh = 0; hh < 4; ++hh)
                wr[hh] = *(const float4*)&W1s[(h0 + hh) * 128 + ((i4 ^ wkey) << 2)];
#pragma unroll
            for (int bb = 0; bb < 4; ++bb)
                pr[bb] = *(const float4*)&poolS[(bb0 + bb) * 128 + ((i4 ^ pkey) << 2)];
#pragma unroll
            for (int bb = 0; bb < 4; ++bb)
#pragma unroll
                for (int hh = 0; hh < 4; ++hh) {
                    acc[bb][hh] = fmaf(pr[bb].x, wr[hh].x, acc[bb][hh]);
                    acc[bb][hh] = fmaf(pr[bb].y, wr[hh].y, acc[bb][hh]);
                    acc[bb][hh] = fmaf(pr[bb].z, wr[hh].z, acc[bb][hh]);
                    acc[bb][hh] = fmaf(pr[bb].w, wr[hh].w, acc[bb][hh]);
                }
        }
        float part[4] = {0.f, 0.f, 0.f, 0.f};
#pragma unroll
        for (int hh = 0; hh < 4; ++hh) {
            float a = A2[h0 + hh], cc = C2[h0 + hh], w2v = w2f[h0 + hh];
#pragma unroll
            for (int bb = 0; bb < 4; ++bb) {
                float h1 = fmaxf(fmaf(acc[bb][hh], a, cc), 0.f);
                part[bb] = fmaf(h1, w2v, part[bb]);
            }
        }
#pragma unroll
        for (int bb = 0; bb < 4; ++bb) red[hx * 33 + bb0 + bb] = part[bb];
    }
    __syncthreads();

    if (tid < 32) {
        float s = 0.f;
#pragma unroll
        for (int j = 0; j < 25; ++j) s += red[j * 33 + tid];
        float A = g3[g] * rsqrtf(v3[g] + EPSf);
        float h2v = fmaxf((s + b2p[g] - m3[g]) * A + be3[g], 0.f);
        h2ws[(size_t)g * Bn + (b0 + tid)] = h2v;   // [g][b], coalesced for stage 3
    }
}

// ---------------- Stage 3: classifier ----------------
__global__ __launch_bounds__(64) void classifier_kernel(
    const float* __restrict__ h2ws, const float* __restrict__ cls_w,
    const float* __restrict__ cls_b, float* __restrict__ out)
{
    const int b = blockIdx.x, t = threadIdx.x;
    float a0 = 0.f, a1 = 0.f;
    for (int gg = t; gg < Gn; gg += 64) {
        float v = h2ws[(size_t)gg * Bn + b];
        a0 = fmaf(v, cls_w[gg], a0);
        a1 = fmaf(v, cls_w[Gn + gg], a1);
    }
#pragma unroll
    for (int off = 32; off; off >>= 1) {
        a0 += __shfl_down(a0, off);
        a1 += __shfl_down(a1, off);
    }
    if (t == 0) {
        out[b * 2 + 0] = a0 + cls_b[0];
        out[b * 2 + 1] = a1 + cls_b[1];
    }
}

extern "C" void kernel_launch(void* const* d_in, const int* in_sizes, int n_in,
                              void* d_out, int out_size, void* d_ws, size_t ws_size,
                              hipStream_t stream) {
    const float* x      = (const float*)d_in[0];
    const float* conv_w = (const float*)d_in[1];
    const float* conv_b = (const float*)d_in[2];
    const float* bn1_g  = (const float*)d_in[3];
    const float* bn1_b  = (const float*)d_in[4];
    const float* bn1_m  = (const float*)d_in[5];
    const float* bn1_v  = (const float*)d_in[6];
    const float* W1     = (const float*)d_in[7];
    const float* b1     = (const float*)d_in[8];
    const float* bn2_g  = (const float*)d_in[9];
    const float* bn2_b  = (const float*)d_in[10];
    const float* bn2_m  = (const float*)d_in[11];
    const float* bn2_v  = (const float*)d_in[12];
    const float* W2     = (const float*)d_in[13];
    const float* b2     = (const float*)d_in[14];
    const float* bn3_g  = (const float*)d_in[15];
    const float* bn3_b  = (const float*)d_in[16];
    const float* bn3_m  = (const float*)d_in[17];
    const float* bn3_v  = (const float*)d_in[18];
    const float* cls_w  = (const float*)d_in[19];
    const float* cls_b  = (const float*)d_in[20];

    float* pooled = (float*)d_ws;                                               // 256*300*100 f32 = 30.72 MB
    float* h2ws   = (float*)((char*)d_ws + (size_t)Bn * Gn * Pn * sizeof(float)); // 300*256 f32

    conv_pool_kernel<<<dim3(Bn, Gn / GB1), 256, 0, stream>>>(
        x, conv_w, conv_b, bn1_g, bn1_b, bn1_m, bn1_v, pooled);

    grouped_mlp_kernel<<<dim3(Gn, 8), 256, 0, stream>>>(
        pooled, W1, b1, bn2_g, bn2_b, bn2_m, bn2_v, W2, b2,
        bn3_g, bn3_b, bn3_m, bn3_v, h2ws);

    classifier_kernel<<<dim3(Bn), 64, 0, stream>>>(h2ws, cls_w, cls_b, (float*)d_out);
}

// Round 3
// 154.353 us; speedup vs baseline: 2.1049x; 2.1049x over previous
//
#include <hip/hip_runtime.h>

// ExplaiNN inference on MFMA (bf16 inputs to matrix cores, f32 accumulate).
// B=256, L=1000, G=300, K=19, HID=100, CLS=2, P=100
//
// prep_x:      x -> 4 phase-shifted bf16 copies xph[b][phi][c][1040] (phi: 8B-alignment phases)
// prep_wc:     conv_w -> bf16 Wc[z][kc][160][8], K=96 layout (c*24+t, taps padded 19->24)
// prep_consts: fold BN1/BN2/BN3 + biases into per-channel scale/bias; W2 copy
// conv_mfma:   implicit-GEMM conv + BN1 + ReLU + maxpool10, M=pool cells, N=groups,
//              K=96, 10 shift-GEMMs (d=0..9) maxed together -> pooled[b][g][p] bf16
// mlp_mfma:    per-group GEMM [128b x 112h x 128i] + BN2/ReLU + W2-dot + BN3/ReLU -> h2ws[g][b] f32
// classifier:  h2 @ cls_w^T + cls_b -> out[256][2] f32

typedef unsigned short ushort_t;
typedef short short8 __attribute__((ext_vector_type(8)));
typedef float floatx4 __attribute__((ext_vector_type(4)));

constexpr float EPSf = 1e-5f;

__device__ __forceinline__ ushort_t f2bf(float f) {
    unsigned u = __float_as_uint(f);
    unsigned r = (u + 0x7FFFu + ((u >> 16) & 1u)) >> 16;   // round-to-nearest-even
    return (ushort_t)r;
}

// ---------------- prep: x phase copies ----------------
// xph[b][phi][c][1040] bf16; copy phi holds x_pad_i[i+phi] where x_pad_i[i] = x[i-9] (zero outside)
__global__ __launch_bounds__(256) void prep_x(const float* __restrict__ x, ushort_t* __restrict__ xph) {
    int idx = blockIdx.x * 256 + threadIdx.x;          // 256*16*1040
    if (idx >= 256 * 16 * 1040) return;
    int i = idx % 1040, r = idx / 1040;
    int c = r & 3, phi = (r >> 2) & 3, b = r >> 4;
    int src = i + phi - 9;
    float v = ((unsigned)src < 1000u) ? x[b * 4000 + c * 1000 + src] : 0.f;
    xph[idx] = f2bf(v);
}

// ---------------- prep: conv weights, B-fragment layout ----------------
// Wc[z][kc][gl][j]: k = kc*8+j in [0,96), c=k/24, t=k%24 (t>=19 -> 0), g = z*160+gl (g>=300 -> 0)
__global__ __launch_bounds__(256) void prep_wc(const float* __restrict__ conv_w, ushort_t* __restrict__ Wc) {
    int idx = blockIdx.x * 256 + threadIdx.x;          // 2*12*160*8 = 61440
    if (idx >= 2 * 12 * 160 * 8) return;
    int j = idx & 7, gl = (idx >> 3) % 160, kc = ((idx >> 3) / 160) % 12, z = idx / (12 * 160 * 8);
    int g = z * 160 + gl, k = kc * 8 + j, c = k / 24, t = k - c * 24;
    float v = (g < 300 && t < 19) ? conv_w[g * 76 + c * 19 + t] : 0.f;
    Wc[idx] = f2bf(v);
}

// ---------------- prep: folded BN constants ----------------
__global__ __launch_bounds__(256) void prep_consts(
    const float* __restrict__ b1, const float* __restrict__ g2, const float* __restrict__ be2,
    const float* __restrict__ m2, const float* __restrict__ v2, const float* __restrict__ W2,
    const float* __restrict__ conv_b, const float* __restrict__ g1, const float* __restrict__ be1,
    const float* __restrict__ m1, const float* __restrict__ v1,
    const float* __restrict__ b2, const float* __restrict__ g3, const float* __restrict__ be3,
    const float* __restrict__ m3, const float* __restrict__ v3,
    float* __restrict__ A2, float* __restrict__ C2, float* __restrict__ w2s,
    float* __restrict__ A1, float* __restrict__ B1, float* __restrict__ A3, float* __restrict__ C3) {
    int idx = blockIdx.x * 256 + threadIdx.x;          // 300*112
    if (idx >= 300 * 112) return;
    int h = idx % 112, g = idx / 112;
    float a2 = 0.f, c2 = 0.f, w2v = 0.f;
    if (h < 100) {
        int q = g * 100 + h;
        a2 = g2[q] * rsqrtf(v2[q] + EPSf);
        c2 = (b1[q] - m2[q]) * a2 + be2[q];
        w2v = W2[q];
    }
    A2[idx] = a2; C2[idx] = c2; w2s[idx] = w2v;
    if (h == 0) {
        float a1 = g1[g] * rsqrtf(v1[g] + EPSf);
        A1[g] = a1; B1[g] = (conv_b[g] - m1[g]) * a1 + be1[g];
        float a3 = g3[g] * rsqrtf(v3[g] + EPSf);
        A3[g] = a3; C3[g] = (b2[g] - m3[g]) * a3 + be3[g];
    }
}

// ---------------- Stage 1: conv via MFMA ----------------
// grid (256 b, 2 p-halves, 2 g-halves), block 256 (4 waves). Wave = one M-tile of 16 pool cells.
// C[m=p][n=g] = sum_k A[m][k] B[k][n]; A[m][(c,t)] = x_pad_i[c][10(p0+m)+d+t]; max over d=0..9.
__global__ __launch_bounds__(256, 2) void conv_mfma(
    const ushort_t* __restrict__ xph, const ushort_t* __restrict__ Wc,
    const float* __restrict__ A1, const float* __restrict__ B1,
    ushort_t* __restrict__ pooled) {
    __shared__ ushort_t Wl[12 * 160 * 8];      // 30720 B, B-frag layout [kc][gl][8]
    __shared__ ushort_t xl[16 * 1040];         // 33280 B, [phi][c][1040]
    __shared__ float A1s[160], B1s[160];

    const int tid = threadIdx.x;
    const int b = blockIdx.x, yw = blockIdx.y, z = blockIdx.z;
    const int gz0 = z * 160;

    {   // linear 16B staging copies (conflict-free)
        const uint4* wsrc = (const uint4*)(Wc + z * 12 * 160 * 8);
        uint4* wdst = (uint4*)Wl;
        for (int i = tid; i < 12 * 160; i += 256) wdst[i] = wsrc[i];
        const uint4* xsrc = (const uint4*)(xph + b * 16 * 1040);
        uint4* xdst = (uint4*)xl;
        for (int i = tid; i < 16 * 1040 / 8; i += 256) xdst[i] = xsrc[i];
        for (int i = tid; i < 160; i += 256) {
            int g = gz0 + i;
            A1s[i] = (g < 300) ? A1[g] : 0.f;
            B1s[i] = (g < 300) ? B1[g] : 0.f;
        }
    }
    __syncthreads();

    const int w = tid >> 6, lane = tid & 63;
    const int p0 = yw * 64 + w * 16;
    if (p0 >= 100) return;                      // no barriers after this point
    const int row = lane & 15, quad = lane >> 4;
    const int p_r = p0 + row;
    const int prc = (p_r < 100) ? p_r : 99;     // clamp keeps LDS reads in-bounds (rows masked at store)

    // A fragments cached for all (d, s): lane holds A[row][32s+quad*8 .. +7]
    uint4 af[10][3];
#pragma unroll
    for (int s = 0; s < 3; ++s) {
        int k0 = s * 32 + quad * 8;
        int c = k0 / 24, t0 = k0 - c * 24;
        int base0 = 10 * prc + t0;
        const ushort_t* xc = &xl[c * 1040];
#pragma unroll
        for (int d = 0; d < 10; ++d) {
            int base = base0 + d;
            int phi = base & 3, bi = base - phi;
            const ushort_t* p = xc + phi * 4160 + bi;   // [phi][c] row, 8B-aligned
            uint2 lo = *(const uint2*)p;
            uint2 hi = *(const uint2*)(p + 4);
            af[d][s] = (uint4){lo.x, lo.y, hi.x, hi.y};
        }
    }

    const int NT = z ? 9 : 10;
    for (int gt = 0; gt < NT; ++gt) {
        short8 bf[3];
#pragma unroll
        for (int s = 0; s < 3; ++s) {
            uint4 t = *(const uint4*)&Wl[(((s * 4 + quad) * 160) + gt * 16 + row) * 8];
            bf[s] = __builtin_bit_cast(short8, t);
        }
        const float a1v = A1s[gt * 16 + row], b1v = B1s[gt * 16 + row];
        floatx4 mx = {0.f, 0.f, 0.f, 0.f};     // ReLU floor
#pragma unroll
        for (int d = 0; d < 10; ++d) {
            floatx4 acc = {0.f, 0.f, 0.f, 0.f};
#pragma unroll
            for (int s = 0; s < 3; ++s)
                acc = __builtin_amdgcn_mfma_f32_16x16x32_bf16(
                    __builtin_bit_cast(short8, af[d][s]), bf[s], acc, 0, 0, 0);
#pragma unroll
            for (int r = 0; r < 4; ++r)
                mx[r] = fmaxf(mx[r], fmaf(acc[r], a1v, b1v));
        }
        const int g = gz0 + gt * 16 + row;      // C col = lane&15
        const int pr0 = p0 + quad * 4;          // C rows = quad*4 + r
        if (g < 300 && pr0 < 100) {
            ushort4 o = make_ushort4(f2bf(mx[0]), f2bf(mx[1]), f2bf(mx[2]), f2bf(mx[3]));
            *(ushort4*)&pooled[((size_t)b * 300 + g) * 100 + pr0] = o;
        }
    }
}

// ---------------- Stage 2: grouped MLP via MFMA ----------------
// grid (300 g, 2 b-halves), block 256. C[m=b][n=h], K=i (128 padded).
__global__ __launch_bounds__(256, 2) void mlp_mfma(
    const ushort_t* __restrict__ pooled, const float* __restrict__ W1,
    const float* __restrict__ A2c, const float* __restrict__ C2c, const float* __restrict__ w2c,
    const float* __restrict__ A3, const float* __restrict__ C3,
    float* __restrict__ h2ws) {
    __shared__ ushort_t W1l[16 * 112 * 8];     // 28672 B, [kc][h][8]
    __shared__ ushort_t pl[128 * 128];         // 32768 B, [bl][chunk^(bl&7)][8]
    __shared__ float A2s[112], C2s[112], w2sl[112];
    __shared__ float sA3, sC3;

    const int tid = threadIdx.x;
    const int g = blockIdx.x, b0 = blockIdx.y * 128;

    {   // zero-fill W1l (pads), then scatter real values
        uint4* wd = (uint4*)W1l;
        for (int i = tid; i < 16 * 112; i += 256) wd[i] = (uint4){0, 0, 0, 0};
    }
    __syncthreads();
    for (int q = tid; q < 2500; q += 256) {    // 4 consecutive i per thread, same h row
        int base = q * 4;
        int h = base / 100, i = base - h * 100;
        float4 v = *(const float4*)&W1[(size_t)g * 10000 + base];
        ushort4 o = make_ushort4(f2bf(v.x), f2bf(v.y), f2bf(v.z), f2bf(v.w));
        *(ushort4*)&W1l[((i >> 3) * 112 + h) * 8 + (i & 7)] = o;   // i&7 in {0,4}: 8B aligned
    }
    for (int q = tid; q < 128 * 16; q += 256) {
        int bl = q >> 4, kc = q & 15;
        const ushort_t* src = pooled + ((size_t)(b0 + bl) * 300 + g) * 100 + kc * 8;
        uint2 lo = *(const uint2*)src;          // rows are 200B apart: 8B-aligned
        uint2 hi = *(const uint2*)(src + 4);    // i>=100 reads spill into next row: finite, x0 by W pad
        int swz = kc ^ (bl & 7);
        *(uint4*)&pl[((bl * 16) + swz) * 8] = (uint4){lo.x, lo.y, hi.x, hi.y};
    }
    if (tid < 112) {
        A2s[tid] = A2c[g * 112 + tid];
        C2s[tid] = C2c[g * 112 + tid];
        w2sl[tid] = w2c[g * 112 + tid];
    }
    if (tid == 0) { sA3 = A3[g]; sC3 = C3[g]; }
    __syncthreads();

    const int w = tid >> 6, lane = tid & 63;
    const int col = lane & 15, quad = lane >> 4;

    short8 bfr[7][4];                          // all B-frags cached (112 VGPR)
#pragma unroll
    for (int nt = 0; nt < 7; ++nt)
#pragma unroll
        for (int s = 0; s < 4; ++s) {
            uint4 t = *(const uint4*)&W1l[(((s * 4 + quad) * 112) + nt * 16 + col) * 8];
            bfr[nt][s] = __builtin_bit_cast(short8, t);
        }

#pragma unroll
    for (int mi = 0; mi < 2; ++mi) {
        const int mt = w * 2 + mi;
        const int bl = mt * 16 + col;          // A row
        uint4 afr[4];
#pragma unroll
        for (int s = 0; s < 4; ++s) {
            int kc = s * 4 + quad;
            afr[s] = *(const uint4*)&pl[((bl * 16) + (kc ^ (bl & 7))) * 8];
        }
        float run0 = 0.f, run1 = 0.f, run2 = 0.f, run3 = 0.f;
#pragma unroll
        for (int nt = 0; nt < 7; ++nt) {
            floatx4 acc = {0.f, 0.f, 0.f, 0.f};
#pragma unroll
            for (int s = 0; s < 4; ++s)
                acc = __builtin_amdgcn_mfma_f32_16x16x32_bf16(
                    __builtin_bit_cast(short8, afr[s]), bfr[nt][s], acc, 0, 0, 0);
            const float a2v = A2s[nt * 16 + col], c2v = C2s[nt * 16 + col], w2v = w2sl[nt * 16 + col];
            run0 += fmaxf(fmaf(acc[0], a2v, c2v), 0.f) * w2v;
            run1 += fmaxf(fmaf(acc[1], a2v, c2v), 0.f) * w2v;
            run2 += fmaxf(fmaf(acc[2], a2v, c2v), 0.f) * w2v;
            run3 += fmaxf(fmaf(acc[3], a2v, c2v), 0.f) * w2v;
        }
#pragma unroll
        for (int m = 1; m <= 8; m <<= 1) {     // sum over the 16 h-cols
            run0 += __shfl_xor(run0, m, 64);
            run1 += __shfl_xor(run1, m, 64);
            run2 += __shfl_xor(run2, m, 64);
            run3 += __shfl_xor(run3, m, 64);
        }
        if (col == 0) {
            float4 o;
            o.x = fmaxf(fmaf(run0, sA3, sC3), 0.f);
            o.y = fmaxf(fmaf(run1, sA3, sC3), 0.f);
            o.z = fmaxf(fmaf(run2, sA3, sC3), 0.f);
            o.w = fmaxf(fmaf(run3, sA3, sC3), 0.f);
            *(float4*)&h2ws[g * 256 + b0 + mt * 16 + quad * 4] = o;
        }
    }
}

// ---------------- Stage 3: classifier ----------------
__global__ __launch_bounds__(64) void classifier_kernel(
    const float* __restrict__ h2ws, const float* __restrict__ cls_w,
    const float* __restrict__ cls_b, float* __restrict__ out) {
    const int b = blockIdx.x, t = threadIdx.x;
    float a0 = 0.f, a1 = 0.f;
    for (int gg = t; gg < 300; gg += 64) {
        float v = h2ws[gg * 256 + b];
        a0 = fmaf(v, cls_w[gg], a0);
        a1 = fmaf(v, cls_w[300 + gg], a1);
    }
#pragma unroll
    for (int off = 32; off; off >>= 1) {
        a0 += __shfl_down(a0, off);
        a1 += __shfl_down(a1, off);
    }
    if (t == 0) {
        out[b * 2 + 0] = a0 + cls_b[0];
        out[b * 2 + 1] = a1 + cls_b[1];
    }
}

extern "C" void kernel_launch(void* const* d_in, const int* in_sizes, int n_in,
                              void* d_out, int out_size, void* d_ws, size_t ws_size,
                              hipStream_t stream) {
    const float* x      = (const float*)d_in[0];
    const float* conv_w = (const float*)d_in[1];
    const float* conv_b = (const float*)d_in[2];
    const float* bn1_g  = (const float*)d_in[3];
    const float* bn1_b  = (const float*)d_in[4];
    const float* bn1_m  = (const float*)d_in[5];
    const float* bn1_v  = (const float*)d_in[6];
    const float* W1     = (const float*)d_in[7];
    const float* b1     = (const float*)d_in[8];
    const float* bn2_g  = (const float*)d_in[9];
    const float* bn2_b  = (const float*)d_in[10];
    const float* bn2_m  = (const float*)d_in[11];
    const float* bn2_v  = (const float*)d_in[12];
    const float* W2     = (const float*)d_in[13];
    const float* b2     = (const float*)d_in[14];
    const float* bn3_g  = (const float*)d_in[15];
    const float* bn3_b  = (const float*)d_in[16];
    const float* bn3_m  = (const float*)d_in[17];
    const float* bn3_v  = (const float*)d_in[18];
    const float* cls_w  = (const float*)d_in[19];
    const float* cls_b  = (const float*)d_in[20];

    char* wsb = (char*)d_ws;
    ushort_t* pooled = (ushort_t*)(wsb);                    // 15,360,000 B
    ushort_t* xph    = (ushort_t*)(wsb + 15360000);         //  8,519,680 B
    ushort_t* Wc     = (ushort_t*)(wsb + 23879680);         //     61,440 B
    float* A2   = (float*)(wsb + 23941120);                 //    134,400 B
    float* C2   = (float*)(wsb + 24075520);
    float* w2s  = (float*)(wsb + 24209920);
    float* A1   = (float*)(wsb + 24344320);                 //      1,200 B each
    float* B1   = (float*)(wsb + 24345520);
    float* A3   = (float*)(wsb + 24346720);
    float* C3   = (float*)(wsb + 24347920);
    float* h2ws = (float*)(wsb + 24349120);                 //    307,200 B

    prep_x<<<dim3((256 * 16 * 1040 + 255) / 256), 256, 0, stream>>>(x, xph);
    prep_wc<<<dim3((2 * 12 * 160 * 8 + 255) / 256), 256, 0, stream>>>(conv_w, Wc);
    prep_consts<<<dim3((300 * 112 + 255) / 256), 256, 0, stream>>>(
        b1, bn2_g, bn2_b, bn2_m, bn2_v, W2,
        conv_b, bn1_g, bn1_b, bn1_m, bn1_v,
        b2, bn3_g, bn3_b, bn3_m, bn3_v,
        A2, C2, w2s, A1, B1, A3, C3);

    conv_mfma<<<dim3(256, 2, 2), 256, 0, stream>>>(xph, Wc, A1, B1, pooled);

    mlp_mfma<<<dim3(300, 2), 256, 0, stream>>>(pooled, W1, A2, C2, w2s, A3, C3, h2ws);

    classifier_kernel<<<dim3(256), 64, 0, stream>>>(h2ws, cls_w, cls_b, (float*)d_out);
}

// Round 4
// 152.222 us; speedup vs baseline: 2.1344x; 1.0140x over previous
//
#include <hip/hip_runtime.h>

// ExplaiNN inference on MFMA (bf16 matrix cores, f32 accumulate). 4 kernels:
// prep_all:  x -> 4 phase-shifted bf16 copies xph[b][phi][c][1040]
//            conv_w -> Wc[kc][304][8] bf16 (K=96: c*24+t, taps 19->24, G pad 304)
//            W1 -> W1b[g][kc][112][8] bf16 (B-fragment layout, coalesced writes)
// conv_mfma: implicit-GEMM conv + BN1 + ReLU + maxpool10 -> pooled[b][g][p] bf16
//            256 blocks (1/CU) x 7 waves; M=16 pool cells/wave, N=304, K=96, 10 shift-GEMMs maxed
// mlp_mfma:  per-group GEMM [128b x 112h x 128i] + BN2/ReLU + W2-dot + BN3/ReLU -> h2ws[g][b] f32
// classifier: h2 @ cls_w^T + cls_b -> out[256][2] f32

typedef unsigned short ushort_t;
typedef short short8 __attribute__((ext_vector_type(8)));
typedef float floatx4 __attribute__((ext_vector_type(4)));

constexpr float EPSf = 1e-5f;

__device__ __forceinline__ ushort_t f2bf(float f) {
    unsigned u = __float_as_uint(f);
    unsigned r = (u + 0x7FFFu + ((u >> 16) & 1u)) >> 16;   // round-to-nearest-even
    return (ushort_t)r;
}

// ---------------- prep: all input transforms, one kernel ----------------
constexpr int T1_BLKS = 8320;   // xph: 2,129,920 uint (2xbf16) writes
constexpr int T2_BLKS = 114;    // Wc: 29,184 ushorts
constexpr int T3_BLKS = 4200;   // W1b: 1,075,200 ushort4 writes
__global__ __launch_bounds__(256) void prep_all(
    const float* __restrict__ x, const float* __restrict__ conv_w, const float* __restrict__ W1,
    ushort_t* __restrict__ xph, ushort_t* __restrict__ Wc, ushort_t* __restrict__ W1b)
{
    const int blk = blockIdx.x, t = threadIdx.x;
    if (blk < T1_BLKS) {
        // xph[b][phi][c][1040], element i holds x[c][i+phi-9] (zero outside); uint = 2 elems
        int u = blk * 256 + t;                       // exact: 8320*256 = 2,129,920
        int iu = u % 520, r = u / 520;
        int c = r & 3, phi = (r >> 2) & 3, b = r >> 4;
        int src = iu * 2 + phi - 9;
        const float* xb = x + b * 4000 + c * 1000;
        float v0 = ((unsigned)src < 1000u) ? xb[src] : 0.f;
        float v1 = ((unsigned)(src + 1) < 1000u) ? xb[src + 1] : 0.f;
        ((unsigned*)xph)[u] = (unsigned)f2bf(v0) | ((unsigned)f2bf(v1) << 16);
    } else if (blk < T1_BLKS + T2_BLKS) {
        int idx = (blk - T1_BLKS) * 256 + t;         // exact: 114*256 = 29,184 = 12*304*8
        int j = idx & 7, g = (idx >> 3) % 304, kc = idx / (304 * 8);
        int k = kc * 8 + j, c = k / 24, tt = k - c * 24;
        float v = (g < 300 && tt < 19) ? conv_w[g * 76 + c * 19 + tt] : 0.f;
        Wc[idx] = f2bf(v);
    } else {
        // W1b[g][kc][h][8]: thread = (g,kc,h,jj) -> ushort4 write, fully coalesced
        int v = (blk - T1_BLKS - T2_BLKS) * 256 + t; // exact: 4200*256 = 1,075,200
        int jj = v & 1, r = v >> 1;
        int h = r % 112, r2 = r / 112;
        int kc = r2 & 15, g = r2 >> 4;
        int i0 = kc * 8 + jj * 4;
        ushort4 o = make_ushort4(0, 0, 0, 0);
        if (h < 100 && i0 <= 96) {
            float4 w = *(const float4*)&W1[(size_t)g * 10000 + h * 100 + i0];
            o = make_ushort4(f2bf(w.x), f2bf(w.y), f2bf(w.z), f2bf(w.w));
        }
        *(ushort4*)&W1b[((size_t)(g * 16 + kc) * 112 + h) * 8 + jj * 4] = o;
    }
}

// ---------------- Stage 1: conv via MFMA ----------------
// grid 256 (one b per block, 1 block/CU), block 448 = 7 waves = 7 M-tiles (p0 = 16w).
// C[m=p][n=g] = sum_k A[m][k] B[k][n]; A[m][(c,t)] = x_pad[c][10(p0+m)+d+t]; max over d=0..9.
__global__ __launch_bounds__(448, 2) void conv_mfma(
    const ushort_t* __restrict__ xph, const ushort_t* __restrict__ Wc,
    const float* __restrict__ conv_b, const float* __restrict__ g1, const float* __restrict__ be1,
    const float* __restrict__ m1, const float* __restrict__ v1,
    ushort_t* __restrict__ pooled)
{
    __shared__ ushort_t Wl[12 * 304 * 8];      // 58368 B, [kc][g][8]
    __shared__ ushort_t xl[16 * 1040];         // 33280 B, [phi][c][1040]
    __shared__ float A1s[304], B1s[304];

    const int tid = threadIdx.x;
    const int b = blockIdx.x;

    {   // linear 16B staging (conflict-free)
        const uint4* wsrc = (const uint4*)Wc;
        uint4* wdst = (uint4*)Wl;
        for (int i = tid; i < 3648; i += 448) wdst[i] = wsrc[i];
        const uint4* xsrc = (const uint4*)(xph + (size_t)b * 16640);
        uint4* xdst = (uint4*)xl;
        for (int i = tid; i < 2080; i += 448) xdst[i] = xsrc[i];
        if (tid < 304) {
            if (tid < 300) {
                float A = g1[tid] * rsqrtf(v1[tid] + EPSf);
                A1s[tid] = A;
                B1s[tid] = (conv_b[tid] - m1[tid]) * A + be1[tid];
            } else { A1s[tid] = 0.f; B1s[tid] = 0.f; }
        }
    }
    __syncthreads();

    const int w = tid >> 6, lane = tid & 63;
    const int p0 = w * 16;                      // 0..96
    const int row = lane & 15, quad = lane >> 4;
    const int p_r = p0 + row;
    const int prc = (p_r < 100) ? p_r : 99;     // clamp keeps LDS reads in-bounds (rows masked at store)

    // A fragments cached for all (d, s): lane holds A[row][32s+quad*8 .. +7]
    uint4 af[10][3];
#pragma unroll
    for (int s = 0; s < 3; ++s) {
        int k0 = s * 32 + quad * 8;
        int c = k0 / 24, t0 = k0 - c * 24;
        int base0 = 10 * prc + t0;
        const ushort_t* xc = &xl[c * 1040];
#pragma unroll
        for (int d = 0; d < 10; ++d) {
            int base = base0 + d;
            int phi = base & 3, bi = base - phi;
            const ushort_t* p = xc + phi * 4160 + bi;   // [phi][c] row, 8B-aligned
            uint2 lo = *(const uint2*)p;
            uint2 hi = *(const uint2*)(p + 4);
            af[d][s] = (uint4){lo.x, lo.y, hi.x, hi.y};
        }
    }

    for (int gt = 0; gt < 19; ++gt) {
        short8 bf[3];
#pragma unroll
        for (int s = 0; s < 3; ++s) {
            uint4 t4 = *(const uint4*)&Wl[(((s * 4 + quad) * 304) + gt * 16 + row) * 8];
            bf[s] = __builtin_bit_cast(short8, t4);
        }
        const float a1v = A1s[gt * 16 + row], b1v = B1s[gt * 16 + row];
        floatx4 mx = {0.f, 0.f, 0.f, 0.f};     // ReLU floor
#pragma unroll
        for (int d = 0; d < 10; ++d) {
            floatx4 acc = {0.f, 0.f, 0.f, 0.f};
#pragma unroll
            for (int s = 0; s < 3; ++s)
                acc = __builtin_amdgcn_mfma_f32_16x16x32_bf16(
                    __builtin_bit_cast(short8, af[d][s]), bf[s], acc, 0, 0, 0);
#pragma unroll
            for (int r = 0; r < 4; ++r)
                mx[r] = fmaxf(mx[r], fmaf(acc[r], a1v, b1v));
        }
        const int g = gt * 16 + row;            // C col = lane&15
        const int pr0 = p0 + quad * 4;          // C rows = quad*4 + r
        if (g < 300 && pr0 < 100) {
            ushort4 o = make_ushort4(f2bf(mx[0]), f2bf(mx[1]), f2bf(mx[2]), f2bf(mx[3]));
            *(ushort4*)&pooled[((size_t)b * 300 + g) * 100 + pr0] = o;
        }
    }
}

// ---------------- Stage 2: grouped MLP via MFMA ----------------
// grid (2 b-halves, 300 g), block 256. C[m=b][n=h], K=i (128 padded).
__global__ __launch_bounds__(256, 2) void mlp_mfma(
    const ushort_t* __restrict__ pooled, const ushort_t* __restrict__ W1b,
    const float* __restrict__ b1, const float* __restrict__ g2, const float* __restrict__ be2,
    const float* __restrict__ m2, const float* __restrict__ v2,
    const float* __restrict__ W2, const float* __restrict__ b2,
    const float* __restrict__ g3, const float* __restrict__ be3,
    const float* __restrict__ m3, const float* __restrict__ v3,
    float* __restrict__ h2ws)
{
    __shared__ ushort_t W1l[16 * 112 * 8];     // 28672 B, [kc][h][8]
    __shared__ ushort_t pl[128 * 128];         // 32768 B, [bl][chunk^(bl&7)][8]
    __shared__ float A2s[112], C2s[112], w2sl[112];
    __shared__ float sA3, sC3;

    const int tid = threadIdx.x;
    const int g = blockIdx.y, b0 = blockIdx.x * 128;

    {   // pure linear copy of prepped B-frag image (conflict-free)
        const uint4* src = (const uint4*)(W1b + (size_t)g * 14336);
        uint4* dst = (uint4*)W1l;
        for (int i = tid; i < 1792; i += 256) dst[i] = src[i];
    }
    for (int q = tid; q < 128 * 16; q += 256) {
        int bl = q >> 4, kc = q & 15;
        const ushort_t* src = pooled + ((size_t)(b0 + bl) * 300 + g) * 100 + kc * 8;
        uint2 lo = *(const uint2*)src;          // rows 200B apart: 8B-aligned
        uint2 hi = *(const uint2*)(src + 4);    // i>=100 spills into next row: finite, x0 by W pad
        int swz = kc ^ (bl & 7);
        *(uint4*)&pl[((bl * 16) + swz) * 8] = (uint4){lo.x, lo.y, hi.x, hi.y};
    }
    if (tid < 112) {
        float a2 = 0.f, c2 = 0.f, w2v = 0.f;
        if (tid < 100) {
            int q = g * 100 + tid;
            a2 = g2[q] * rsqrtf(v2[q] + EPSf);
            c2 = (b1[q] - m2[q]) * a2 + be2[q];
            w2v = W2[q];
        }
        A2s[tid] = a2; C2s[tid] = c2; w2sl[tid] = w2v;
    }
    if (tid == 0) {
        float a3 = g3[g] * rsqrtf(v3[g] + EPSf);
        sA3 = a3; sC3 = (b2[g] - m3[g]) * a3 + be3[g];
    }
    __syncthreads();

    const int w = tid >> 6, lane = tid & 63;
    const int col = lane & 15, quad = lane >> 4;

    short8 bfr[7][4];                          // all B-frags cached (112 VGPR)
#pragma unroll
    for (int nt = 0; nt < 7; ++nt)
#pragma unroll
        for (int s = 0; s < 4; ++s) {
            uint4 t4 = *(const uint4*)&W1l[(((s * 4 + quad) * 112) + nt * 16 + col) * 8];
            bfr[nt][s] = __builtin_bit_cast(short8, t4);
        }

#pragma unroll
    for (int mi = 0; mi < 2; ++mi) {
        const int mt = w * 2 + mi;
        const int bl = mt * 16 + col;          // A row
        uint4 afr[4];
#pragma unroll
        for (int s = 0; s < 4; ++s) {
            int kc = s * 4 + quad;
            afr[s] = *(const uint4*)&pl[((bl * 16) + (kc ^ (bl & 7))) * 8];
        }
        float run0 = 0.f, run1 = 0.f, run2 = 0.f, run3 = 0.f;
#pragma unroll
        for (int nt = 0; nt < 7; ++nt) {
            floatx4 acc = {0.f, 0.f, 0.f, 0.f};
#pragma unroll
            for (int s = 0; s < 4; ++s)
                acc = __builtin_amdgcn_mfma_f32_16x16x32_bf16(
                    __builtin_bit_cast(short8, afr[s]), bfr[nt][s], acc, 0, 0, 0);
            const float a2v = A2s[nt * 16 + col], c2v = C2s[nt * 16 + col], w2v = w2sl[nt * 16 + col];
            run0 += fmaxf(fmaf(acc[0], a2v, c2v), 0.f) * w2v;
            run1 += fmaxf(fmaf(acc[1], a2v, c2v), 0.f) * w2v;
            run2 += fmaxf(fmaf(acc[2], a2v, c2v), 0.f) * w2v;
            run3 += fmaxf(fmaf(acc[3], a2v, c2v), 0.f) * w2v;
        }
#pragma unroll
        for (int m = 1; m <= 8; m <<= 1) {     // sum over the 16 h-cols
            run0 += __shfl_xor(run0, m, 64);
            run1 += __shfl_xor(run1, m, 64);
            run2 += __shfl_xor(run2, m, 64);
            run3 += __shfl_xor(run3, m, 64);
        }
        if (col == 0) {
            float4 o;
            o.x = fmaxf(fmaf(run0, sA3, sC3), 0.f);
            o.y = fmaxf(fmaf(run1, sA3, sC3), 0.f);
            o.z = fmaxf(fmaf(run2, sA3, sC3), 0.f);
            o.w = fmaxf(fmaf(run3, sA3, sC3), 0.f);
            *(float4*)&h2ws[g * 256 + b0 + mt * 16 + quad * 4] = o;
        }
    }
}

// ---------------- Stage 3: classifier ----------------
__global__ __launch_bounds__(64) void classifier_kernel(
    const float* __restrict__ h2ws, const float* __restrict__ cls_w,
    const float* __restrict__ cls_b, float* __restrict__ out) {
    const int b = blockIdx.x, t = threadIdx.x;
    float a0 = 0.f, a1 = 0.f;
    for (int gg = t; gg < 300; gg += 64) {
        float v = h2ws[gg * 256 + b];
        a0 = fmaf(v, cls_w[gg], a0);
        a1 = fmaf(v, cls_w[300 + gg], a1);
    }
#pragma unroll
    for (int off = 32; off; off >>= 1) {
        a0 += __shfl_down(a0, off);
        a1 += __shfl_down(a1, off);
    }
    if (t == 0) {
        out[b * 2 + 0] = a0 + cls_b[0];
        out[b * 2 + 1] = a1 + cls_b[1];
    }
}

extern "C" void kernel_launch(void* const* d_in, const int* in_sizes, int n_in,
                              void* d_out, int out_size, void* d_ws, size_t ws_size,
                              hipStream_t stream) {
    const float* x      = (const float*)d_in[0];
    const float* conv_w = (const float*)d_in[1];
    const float* conv_b = (const float*)d_in[2];
    const float* bn1_g  = (const float*)d_in[3];
    const float* bn1_b  = (const float*)d_in[4];
    const float* bn1_m  = (const float*)d_in[5];
    const float* bn1_v  = (const float*)d_in[6];
    const float* W1     = (const float*)d_in[7];
    const float* b1     = (const float*)d_in[8];
    const float* bn2_g  = (const float*)d_in[9];
    const float* bn2_b  = (const float*)d_in[10];
    const float* bn2_m  = (const float*)d_in[11];
    const float* bn2_v  = (const float*)d_in[12];
    const float* W2     = (const float*)d_in[13];
    const float* b2     = (const float*)d_in[14];
    const float* bn3_g  = (const float*)d_in[15];
    const float* bn3_b  = (const float*)d_in[16];
    const float* bn3_m  = (const float*)d_in[17];
    const float* bn3_v  = (const float*)d_in[18];
    const float* cls_w  = (const float*)d_in[19];
    const float* cls_b  = (const float*)d_in[20];

    char* wsb = (char*)d_ws;
    ushort_t* pooled = (ushort_t*)(wsb);                    // 15,360,000 B (over-read <256B lands in xph: finite)
    ushort_t* xph    = (ushort_t*)(wsb + 15360000);         //  8,519,680 B
    ushort_t* Wc     = (ushort_t*)(wsb + 23879680);         //     58,368 B
    ushort_t* W1b    = (ushort_t*)(wsb + 23938048);         //  8,601,600 B
    float*    h2ws   = (float*)  (wsb + 32539648);          //    307,200 B

    prep_all<<<dim3(T1_BLKS + T2_BLKS + T3_BLKS), 256, 0, stream>>>(x, conv_w, W1, xph, Wc, W1b);

    conv_mfma<<<dim3(256), 448, 0, stream>>>(
        xph, Wc, conv_b, bn1_g, bn1_b, bn1_m, bn1_v, pooled);

    mlp_mfma<<<dim3(2, 300), 256, 0, stream>>>(
        pooled, W1b, b1, bn2_g, bn2_b, bn2_m, bn2_v, W2, b2,
        bn3_g, bn3_b, bn3_m, bn3_v, h2ws);

    classifier_kernel<<<dim3(256), 64, 0, stream>>>(h2ws, cls_w, cls_b, (float*)d_out);
}

// Round 5
// 145.866 us; speedup vs baseline: 2.2274x; 1.0436x over previous
//
#include <hip/hip_runtime.h>

// ExplaiNN inference on MFMA (bf16 matrix cores, f32 accumulate). 4 kernels:
// prep_all:  conv_w -> Wc[kc][304][8] bf16 (K=96: c*24+t, taps 19->24, G pad 304)
//            W1 -> W1b[g][kc][112][8] bf16 (B-fragment layout, XCD-local g blocks)
// conv_mfma: implicit-GEMM conv + BN1 + ReLU + maxpool10 -> pooled[b][g][p] bf16
//            grid (256 b, 2 p-windows), 256 thr, 2 blocks/CU (staging overlaps compute).
//            x staged f32->bf16 directly into 4 phase-shifted LDS copies (no global xph).
// mlp_mfma:  per-group GEMM [128b x 112h x 128i] + BN2/ReLU + W2-dot + BN3/ReLU -> h2ws[g][b]
//            1-D grid 608, XCD-swizzled so both b-halves of a g share one XCD's L2.
// classifier: h2 @ cls_w^T + cls_b -> out[256][2] f32

typedef unsigned short ushort_t;
typedef short short8 __attribute__((ext_vector_type(8)));
typedef float floatx4 __attribute__((ext_vector_type(4)));

constexpr float EPSf = 1e-5f;

__device__ __forceinline__ ushort_t f2bf(float f) {
    unsigned u = __float_as_uint(f);
    unsigned r = (u + 0x7FFFu + ((u >> 16) & 1u)) >> 16;   // round-to-nearest-even
    return (ushort_t)r;
}

// ---------------- prep: weight transforms ----------------
constexpr int WC_BLKS  = 114;    // 29,184 ushorts = 12*304*8
constexpr int W1B_BLKS = 4256;   // 8 xcd * 38 g * 14 blocks (3584 thr/g = 16kc*112h*2jj)
__global__ __launch_bounds__(256) void prep_all(
    const float* __restrict__ conv_w, const float* __restrict__ W1,
    ushort_t* __restrict__ Wc, ushort_t* __restrict__ W1b)
{
    const int blk = blockIdx.x, t = threadIdx.x;
    if (blk < WC_BLKS) {
        int idx = blk * 256 + t;                     // exact: 114*256 = 29,184
        int j = idx & 7, g = (idx >> 3) % 304, kc = idx / (304 * 8);
        int k = kc * 8 + j, c = k / 24, tt = k - c * 24;
        float v = (g < 300 && tt < 19) ? conv_w[g * 76 + c * 19 + tt] : 0.f;
        Wc[idx] = f2bf(v);
    } else {
        // W1b[g][kc][h][8]; blk&7 selects XCD-local g range (38 g per XCD slice)
        int blk2 = blk - WC_BLKS;
        int xcd = blk2 & 7, j = blk2 >> 3;
        int gl = j / 14, inner = j - gl * 14;
        int g = xcd * 38 + gl;
        if (g >= 300) return;
        int v = inner * 256 + t;                     // 0..3583
        int jj = v & 1, r = v >> 1;
        int h = r % 112, kc = r / 112;
        int i0 = kc * 8 + jj * 4;
        ushort4 o = make_ushort4(0, 0, 0, 0);
        if (h < 100 && i0 <= 96) {
            float4 w = *(const float4*)&W1[(size_t)g * 10000 + h * 100 + i0];
            o = make_ushort4(f2bf(w.x), f2bf(w.y), f2bf(w.z), f2bf(w.w));
        }
        *(ushort4*)&W1b[((size_t)(g * 16 + kc) * 112 + h) * 8 + jj * 4] = o;
    }
}

// ---------------- Stage 1: conv via MFMA ----------------
// Window q=0: p 0..51 (4 M-tiles), q=1: p 52..99 (3 M-tiles). X0 = x_pad origin of LDS window.
// C[m=p][n=g] = sum_k A[m][k] B[k][n]; A[m][(c,t)] = x_pad[c][10(p)+d+t]; max over d=0..9.
__global__ __launch_bounds__(256, 2) void conv_mfma(
    const float* __restrict__ x, const ushort_t* __restrict__ Wc,
    const float* __restrict__ conv_b, const float* __restrict__ g1, const float* __restrict__ be1,
    const float* __restrict__ m1, const float* __restrict__ v1,
    ushort_t* __restrict__ pooled)
{
    __shared__ ushort_t Wl[12 * 304 * 8];      // 58368 B, [kc][g][8]
    __shared__ ushort_t xl[16 * 552];          // 17664 B, [(phi*4+c)][552], phase-shifted copies
    __shared__ float A1s[304], B1s[304];

    const int tid = threadIdx.x;
    const int b = blockIdx.x, q = blockIdx.y;
    const int X0 = q * 520;                     // x_pad coordinate of xl[.][0]

    // stage x (f32 global) -> 4 phase copies bf16 in LDS; copy phi elem i = x_pad[X0+i+phi]
    for (int u = tid; u < 16 * 276; u += 256) { // uint = 2 bf16
        int iu = u % 276, r = u / 276;
        int c = r & 3, phi = r >> 2;
        int gi = X0 + 2 * iu + phi - 9;         // x index of low element
        const float* xb = x + b * 4000 + c * 1000;
        float v0 = ((unsigned)gi < 1000u) ? xb[gi] : 0.f;
        float v1_ = ((unsigned)(gi + 1) < 1000u) ? xb[gi + 1] : 0.f;
        ((unsigned*)xl)[u] = (unsigned)f2bf(v0) | ((unsigned)f2bf(v1_) << 16);
    }
    {   // weights: linear 16B copy (L2-resident, conflict-free)
        const uint4* wsrc = (const uint4*)Wc;
        uint4* wdst = (uint4*)Wl;
        for (int i = tid; i < 3648; i += 256) wdst[i] = wsrc[i];
    }
    for (int i = tid; i < 304; i += 256) {
        if (i < 300) {
            float A = g1[i] * rsqrtf(v1[i] + EPSf);
            A1s[i] = A;
            B1s[i] = (conv_b[i] - m1[i]) * A + be1[i];
        } else { A1s[i] = 0.f; B1s[i] = 0.f; }
    }
    __syncthreads();

    const int w = tid >> 6, lane = tid & 63;
    if (q == 1 && w == 3) return;               // 3 tiles in window 1; no barriers after this
    const int p0 = q ? (52 + w * 16) : (w * 16);
    const int pmax = q ? 99 : 51;
    const int row = lane & 15, quad = lane >> 4;
    const int p_r = p0 + row;
    const int prc = (p_r < pmax) ? p_r : pmax;  // clamp keeps LDS reads in window (rows masked at store)

    // A fragments cached for all (d, s): lane holds A[row][32s+quad*8 .. +7]
    uint4 af[10][3];
#pragma unroll
    for (int s = 0; s < 3; ++s) {
        int k0 = s * 32 + quad * 8;
        int c = k0 / 24, t0 = k0 - c * 24;
        int base0 = 10 * prc + t0 - X0;         // local window coords, max 542 (q0) / 502 (q1)
#pragma unroll
        for (int d = 0; d < 10; ++d) {
            int local = base0 + d;
            int phi = local & 3, bi = local - phi;
            const ushort_t* p = &xl[(phi * 4 + c) * 552 + bi];  // 8B-aligned
            uint2 lo = *(const uint2*)p;
            uint2 hi = *(const uint2*)(p + 4);
            af[d][s] = (uint4){lo.x, lo.y, hi.x, hi.y};
        }
    }

    for (int gt = 0; gt < 19; ++gt) {
        short8 bf[3];
#pragma unroll
        for (int s = 0; s < 3; ++s) {
            uint4 t4 = *(const uint4*)&Wl[(((s * 4 + quad) * 304) + gt * 16 + row) * 8];
            bf[s] = __builtin_bit_cast(short8, t4);
        }
        const float a1v = A1s[gt * 16 + row], b1v = B1s[gt * 16 + row];
        floatx4 mx = {0.f, 0.f, 0.f, 0.f};     // ReLU floor
#pragma unroll
        for (int d = 0; d < 10; ++d) {
            floatx4 acc = {0.f, 0.f, 0.f, 0.f};
#pragma unroll
            for (int s = 0; s < 3; ++s)
                acc = __builtin_amdgcn_mfma_f32_16x16x32_bf16(
                    __builtin_bit_cast(short8, af[d][s]), bf[s], acc, 0, 0, 0);
#pragma unroll
            for (int r = 0; r < 4; ++r)
                mx[r] = fmaxf(mx[r], fmaf(acc[r], a1v, b1v));
        }
        const int g = gt * 16 + row;            // C col = lane&15
        const int pr0 = p0 + quad * 4;          // C rows = quad*4 + r
        if (g < 300 && pr0 + 3 <= pmax) {
            ushort4 o = make_ushort4(f2bf(mx[0]), f2bf(mx[1]), f2bf(mx[2]), f2bf(mx[3]));
            *(ushort4*)&pooled[((size_t)b * 300 + g) * 100 + pr0] = o;
        }
    }
}

// ---------------- Stage 2: grouped MLP via MFMA ----------------
// grid 608: blk&7 = XCD slice, 38 g each, 2 b-halves per g on the same slice.
__global__ __launch_bounds__(256, 2) void mlp_mfma(
    const ushort_t* __restrict__ pooled, const ushort_t* __restrict__ W1b,
    const float* __restrict__ b1, const float* __restrict__ g2, const float* __restrict__ be2,
    const float* __restrict__ m2, const float* __restrict__ v2,
    const float* __restrict__ W2, const float* __restrict__ b2,
    const float* __restrict__ g3, const float* __restrict__ be3,
    const float* __restrict__ m3, const float* __restrict__ v3,
    float* __restrict__ h2ws)
{
    __shared__ ushort_t W1l[16 * 112 * 8];     // 28672 B, [kc][h][8]
    __shared__ ushort_t pl[128 * 128];         // 32768 B, [bl][chunk^(bl&7)][8]
    __shared__ float A2s[112], C2s[112], w2sl[112];
    __shared__ float sA3, sC3;

    const int tid = threadIdx.x;
    const int blk = blockIdx.x;
    const int xcd = blk & 7, j = blk >> 3;
    const int g = xcd * 38 + (j >> 1);
    if (g >= 300) return;
    const int b0 = (j & 1) * 128;

    {   // pure linear copy of prepped B-frag image (conflict-free)
        const uint4* src = (const uint4*)(W1b + (size_t)g * 14336);
        uint4* dst = (uint4*)W1l;
        for (int i = tid; i < 1792; i += 256) dst[i] = src[i];
    }
    for (int q = tid; q < 128 * 16; q += 256) {
        int bl = q >> 4, kc = q & 15;
        const ushort_t* src = pooled + ((size_t)(b0 + bl) * 300 + g) * 100 + kc * 8;
        uint2 lo = *(const uint2*)src;          // rows 200B apart: 8B-aligned
        uint2 hi = *(const uint2*)(src + 4);    // i>=100 spills into next row (finite, x0 by W pad)
        int swz = kc ^ (bl & 7);
        *(uint4*)&pl[((bl * 16) + swz) * 8] = (uint4){lo.x, lo.y, hi.x, hi.y};
    }
    if (tid < 112) {
        float a2 = 0.f, c2 = 0.f, w2v = 0.f;
        if (tid < 100) {
            int qq = g * 100 + tid;
            a2 = g2[qq] * rsqrtf(v2[qq] + EPSf);
            c2 = (b1[qq] - m2[qq]) * a2 + be2[qq];
            w2v = W2[qq];
        }
        A2s[tid] = a2; C2s[tid] = c2; w2sl[tid] = w2v;
    }
    if (tid == 0) {
        float a3 = g3[g] * rsqrtf(v3[g] + EPSf);
        sA3 = a3; sC3 = (b2[g] - m3[g]) * a3 + be3[g];
    }
    __syncthreads();

    const int w = tid >> 6, lane = tid & 63;
    const int col = lane & 15, quad = lane >> 4;

    short8 bfr[7][4];                          // all B-frags cached (112 VGPR)
#pragma unroll
    for (int nt = 0; nt < 7; ++nt)
#pragma unroll
        for (int s = 0; s < 4; ++s) {
            uint4 t4 = *(const uint4*)&W1l[(((s * 4 + quad) * 112) + nt * 16 + col) * 8];
            bfr[nt][s] = __builtin_bit_cast(short8, t4);
        }

#pragma unroll
    for (int mi = 0; mi < 2; ++mi) {
        const int mt = w * 2 + mi;
        const int bl = mt * 16 + col;          // A row
        uint4 afr[4];
#pragma unroll
        for (int s = 0; s < 4; ++s) {
            int kc = s * 4 + quad;
            afr[s] = *(const uint4*)&pl[((bl * 16) + (kc ^ (bl & 7))) * 8];
        }
        float run0 = 0.f, run1 = 0.f, run2 = 0.f, run3 = 0.f;
#pragma unroll
        for (int nt = 0; nt < 7; ++nt) {
            floatx4 acc = {0.f, 0.f, 0.f, 0.f};
#pragma unroll
            for (int s = 0; s < 4; ++s)
                acc = __builtin_amdgcn_mfma_f32_16x16x32_bf16(
                    __builtin_bit_cast(short8, afr[s]), bfr[nt][s], acc, 0, 0, 0);
            const float a2v = A2s[nt * 16 + col], c2v = C2s[nt * 16 + col], w2v = w2sl[nt * 16 + col];
            run0 += fmaxf(fmaf(acc[0], a2v, c2v), 0.f) * w2v;
            run1 += fmaxf(fmaf(acc[1], a2v, c2v), 0.f) * w2v;
            run2 += fmaxf(fmaf(acc[2], a2v, c2v), 0.f) * w2v;
            run3 += fmaxf(fmaf(acc[3], a2v, c2v), 0.f) * w2v;
        }
#pragma unroll
        for (int m = 1; m <= 8; m <<= 1) {     // sum over the 16 h-cols
            run0 += __shfl_xor(run0, m, 64);
            run1 += __shfl_xor(run1, m, 64);
            run2 += __shfl_xor(run2, m, 64);
            run3 += __shfl_xor(run3, m, 64);
        }
        if (col == 0) {
            float4 o;
            o.x = fmaxf(fmaf(run0, sA3, sC3), 0.f);
            o.y = fmaxf(fmaf(run1, sA3, sC3), 0.f);
            o.z = fmaxf(fmaf(run2, sA3, sC3), 0.f);
            o.w = fmaxf(fmaf(run3, sA3, sC3), 0.f);
            *(float4*)&h2ws[g * 256 + b0 + mt * 16 + quad * 4] = o;
        }
    }
}

// ---------------- Stage 3: classifier ----------------
__global__ __launch_bounds__(64) void classifier_kernel(
    const float* __restrict__ h2ws, const float* __restrict__ cls_w,
    const float* __restrict__ cls_b, float* __restrict__ out) {
    const int b = blockIdx.x, t = threadIdx.x;
    float a0 = 0.f, a1 = 0.f;
    for (int gg = t; gg < 300; gg += 64) {
        float v = h2ws[gg * 256 + b];
        a0 = fmaf(v, cls_w[gg], a0);
        a1 = fmaf(v, cls_w[300 + gg], a1);
    }
#pragma unroll
    for (int off = 32; off; off >>= 1) {
        a0 += __shfl_down(a0, off);
        a1 += __shfl_down(a1, off);
    }
    if (t == 0) {
        out[b * 2 + 0] = a0 + cls_b[0];
        out[b * 2 + 1] = a1 + cls_b[1];
    }
}

extern "C" void kernel_launch(void* const* d_in, const int* in_sizes, int n_in,
                              void* d_out, int out_size, void* d_ws, size_t ws_size,
                              hipStream_t stream) {
    const float* x      = (const float*)d_in[0];
    const float* conv_w = (const float*)d_in[1];
    const float* conv_b = (const float*)d_in[2];
    const float* bn1_g  = (const float*)d_in[3];
    const float* bn1_b  = (const float*)d_in[4];
    const float* bn1_m  = (const float*)d_in[5];
    const float* bn1_v  = (const float*)d_in[6];
    const float* W1     = (const float*)d_in[7];
    const float* b1     = (const float*)d_in[8];
    const float* bn2_g  = (const float*)d_in[9];
    const float* bn2_b  = (const float*)d_in[10];
    const float* bn2_m  = (const float*)d_in[11];
    const float* bn2_v  = (const float*)d_in[12];
    const float* W2     = (const float*)d_in[13];
    const float* b2     = (const float*)d_in[14];
    const float* bn3_g  = (const float*)d_in[15];
    const float* bn3_b  = (const float*)d_in[16];
    const float* bn3_m  = (const float*)d_in[17];
    const float* bn3_v  = (const float*)d_in[18];
    const float* cls_w  = (const float*)d_in[19];
    const float* cls_b  = (const float*)d_in[20];

    char* wsb = (char*)d_ws;
    ushort_t* pooled = (ushort_t*)(wsb);                 // 15,360,000 B (spill <256B lands in Wc: finite)
    ushort_t* Wc     = (ushort_t*)(wsb + 15360000);      //     58,368 B
    ushort_t* W1b    = (ushort_t*)(wsb + 15418368);      //  8,601,600 B
    float*    h2ws   = (float*)  (wsb + 24019968);       //    307,200 B

    prep_all<<<dim3(WC_BLKS + W1B_BLKS), 256, 0, stream>>>(conv_w, W1, Wc, W1b);

    conv_mfma<<<dim3(256, 2), 256, 0, stream>>>(
        x, Wc, conv_b, bn1_g, bn1_b, bn1_m, bn1_v, pooled);

    mlp_mfma<<<dim3(608), 256, 0, stream>>>(
        pooled, W1b, b1, bn2_g, bn2_b, bn2_m, bn2_v, W2, b2,
        bn3_g, bn3_b, bn3_m, bn3_v, h2ws);

    classifier_kernel<<<dim3(256), 64, 0, stream>>>(h2ws, cls_w, cls_b, (float*)d_out);
}